// Round 1
// baseline (237.286 us; speedup 1.0000x reference)
//
#include <hip/hip_runtime.h>

// NetVLAD fused kernel for MI355X (gfx950).
// Shapes: x[N=64][C=128][S=4096] fp32, conv_w[K=64][C=128], centroids[K=64][C=128].
// out[N][K*C] fp32.
//
// Plan:
//   memset ws (vlad[N][K][C] fp32 accum + asum[N][K])
//   netvlad_main: per (n, 512-pixel slab): loop 8 chunks of 64 px:
//     stage x -> LDS bf16 in two layouts (x_sc: [s][c] for P1 B-frags,
//     x_cs: [c][s] for P3 B-frags, built via LDS transpose)
//     P1: logits = W @ X   (MFMA 16x16x32 bf16, W frags preloaded in regs)
//     softmax over K entirely in-wave (each wave owns full k for its s-tile)
//     P3: vlad += A @ X^T  (MFMA, persistent accumulators across chunks)
//   block end: atomicAdd vlad partials + asum partials
//   netvlad_epilogue: v = vlad - asum*centroid; intra-L2 norm per (n,k);
//     global norm is exactly sqrt(K)=8 (rows are unit norm), so scale 0.125.

#define Nn 64
#define Cc 128
#define Ss 4096
#define Kk 64
#define TS 64
#define CH 8
#define SB (TS*CH)

typedef __attribute__((ext_vector_type(8))) short bf16x8;
typedef __attribute__((ext_vector_type(4))) float f32x4;

__device__ __forceinline__ unsigned short f2bf(float f) {
  unsigned u = __float_as_uint(f);
  u = (u + 0x7FFFu + ((u >> 16) & 1u)) >> 16;  // RNE
  return (unsigned short)u;
}

// LDS strides in halves. Chosen so rows are 16B-multiples (b128-alignable)
// and column accesses land ~2-way on banks (free per m136).
#define XSC_STR 136   // x_sc[64][136]: 272B rows
#define XCS_STR 72    // x_cs[128][72]: 144B rows
#define AKS_STR 72    // a_ks[64][72]

__launch_bounds__(256, 2)
__global__ void netvlad_main(const float* __restrict__ x,
                             const float* __restrict__ w,
                             float* __restrict__ vlad,   // [N][K][C] fp32, pre-zeroed
                             float* __restrict__ asum)   // [N][K] fp32, pre-zeroed
{
  __shared__ __align__(16) unsigned short x_sc[TS][XSC_STR];  // x[s][c]
  __shared__ __align__(16) unsigned short x_cs[Cc][XCS_STR];  // x[c][s]
  __shared__ __align__(16) unsigned short a_ks[Kk][AKS_STR];  // a[k][s]

  const int t   = threadIdx.x;
  const int wv  = t >> 6;          // wave 0..3
  const int l15 = t & 15;
  const int l4  = (t >> 4) & 3;    // lane quad within wave
  const int n   = blockIdx.y;
  const int sb  = blockIdx.x;      // s-slab 0..7
  const size_t xbase = (size_t)n * Cc * Ss;

  // ---- preload W fragments into registers (A-operand of P1) ----
  // A[m=k][kd=c]: lane holds A[16*mt + l15][32*q + 8*l4 + j], j=0..7
  bf16x8 wfrag[4][4];
#pragma unroll
  for (int mt = 0; mt < 4; ++mt) {
#pragma unroll
    for (int q = 0; q < 4; ++q) {
      const float* wp = w + (16*mt + l15) * Cc + 32*q + 8*l4;
      float4 a = *(const float4*)wp;
      float4 b = *(const float4*)(wp + 4);
      bf16x8 f;
      f[0] = (short)f2bf(a.x); f[1] = (short)f2bf(a.y);
      f[2] = (short)f2bf(a.z); f[3] = (short)f2bf(a.w);
      f[4] = (short)f2bf(b.x); f[5] = (short)f2bf(b.y);
      f[6] = (short)f2bf(b.z); f[7] = (short)f2bf(b.w);
      wfrag[mt][q] = f;
    }
  }

  // persistent accumulators
  f32x4 acc3[4][2];                 // [mt(k-tile)][tc(c-tile within wave's 32c)]
#pragma unroll
  for (int mt = 0; mt < 4; ++mt)
#pragma unroll
    for (int tc = 0; tc < 2; ++tc) acc3[mt][tc] = (f32x4){0.f,0.f,0.f,0.f};
  float asum_reg[4][4];             // [mt][r]
#pragma unroll
  for (int mt = 0; mt < 4; ++mt)
#pragma unroll
    for (int r = 0; r < 4; ++r) asum_reg[mt][r] = 0.f;

  for (int ch = 0; ch < CH; ++ch) {
    const int s0 = sb * SB + ch * TS;

    // ---- stage pass 1: global fp32 -> x_cs bf16 ([c][s], natural layout) ----
    {
      const int s4 = 4 * (t & 15);
      const int cb = t >> 4;               // 0..15
#pragma unroll
      for (int it = 0; it < 8; ++it) {
        const int c = cb + 16 * it;
        float4 v = *(const float4*)(x + xbase + (size_t)c * Ss + s0 + s4);
        unsigned p0 = (unsigned)f2bf(v.x) | ((unsigned)f2bf(v.y) << 16);
        unsigned p1 = (unsigned)f2bf(v.z) | ((unsigned)f2bf(v.w) << 16);
        unsigned short* dst = &x_cs[c][s4];
        *(int2*)dst = make_int2((int)p0, (int)p1);
      }
    }
    __syncthreads();

    // ---- stage pass 2: LDS transpose x_cs -> x_sc ([s][c]) ----
    {
      const int s = t & 63;
#pragma unroll
      for (int j = 0; j < 4; ++j) {
        const int c8 = 8 * wv + 32 * j;
        unsigned short h[8];
        // rotate i by wave to kill the 8-way bank conflict
#pragma unroll
        for (int i = 0; i < 8; ++i) {
          const int i2 = (i + 2 * wv) & 7;
          h[i2] = x_cs[c8 + i2][s];
        }
        unsigned p0 = (unsigned)h[0] | ((unsigned)h[1] << 16);
        unsigned p1 = (unsigned)h[2] | ((unsigned)h[3] << 16);
        unsigned p2 = (unsigned)h[4] | ((unsigned)h[5] << 16);
        unsigned p3 = (unsigned)h[6] | ((unsigned)h[7] << 16);
        *(int4*)&x_sc[s][c8] = make_int4((int)p0, (int)p1, (int)p2, (int)p3);
      }
    }
    __syncthreads();

    // ---- P1: logits tile. wave wv owns s-tile [16*wv,16*wv+16), all 64 k ----
    f32x4 acc1[4];
#pragma unroll
    for (int mt = 0; mt < 4; ++mt) acc1[mt] = (f32x4){0.f,0.f,0.f,0.f};
#pragma unroll
    for (int q = 0; q < 4; ++q) {
      // B[kd=c][nn=s]: lane holds x[32q+8*l4+j][16*wv+l15] = x_sc[16*wv+l15][...]
      bf16x8 bfr = *(bf16x8*)&x_sc[16*wv + l15][32*q + 8*l4];
#pragma unroll
      for (int mt = 0; mt < 4; ++mt)
        acc1[mt] = __builtin_amdgcn_mfma_f32_16x16x32_bf16(wfrag[mt][q], bfr, acc1[mt], 0, 0, 0);
    }

    // ---- softmax over k, fully in-wave (wave holds full k for its columns) ----
    // C/D layout: col s = 16*wv + l15, row k = 16*mt + 4*l4 + r
    float e[4][4];
    float cs = 0.f;
#pragma unroll
    for (int mt = 0; mt < 4; ++mt)
#pragma unroll
      for (int r = 0; r < 4; ++r) {
        float ev = __expf(acc1[mt][r]);   // |logit| ~ <5, no max-sub needed
        e[mt][r] = ev;
        cs += ev;
      }
    cs += __shfl_xor(cs, 16, 64);
    cs += __shfl_xor(cs, 32, 64);
    const float inv = 1.0f / cs;
#pragma unroll
    for (int mt = 0; mt < 4; ++mt)
#pragma unroll
      for (int r = 0; r < 4; ++r) {
        float an = e[mt][r] * inv;
        asum_reg[mt][r] += an;
        a_ks[16*mt + 4*l4 + r][16*wv + l15] = f2bf(an);
      }
    __syncthreads();

    // ---- P3: vlad += A @ X^T. wave wv owns c in [32*wv, 32*wv+32) ----
#pragma unroll
    for (int q2 = 0; q2 < 2; ++q2) {
      bf16x8 afr[4];
#pragma unroll
      for (int mt = 0; mt < 4; ++mt)
        afr[mt] = *(bf16x8*)&a_ks[16*mt + l15][32*q2 + 8*l4];
#pragma unroll
      for (int tc = 0; tc < 2; ++tc) {
        // B[kd=s][nn=c]: lane holds x^T[32q2+8*l4+j][32*wv+16*tc+l15] = x_cs[c][s]
        bf16x8 bfr = *(bf16x8*)&x_cs[32*wv + 16*tc + l15][32*q2 + 8*l4];
#pragma unroll
        for (int mt = 0; mt < 4; ++mt)
          acc3[mt][tc] = __builtin_amdgcn_mfma_f32_16x16x32_bf16(afr[mt], bfr, acc3[mt][tc], 0, 0, 0);
      }
    }
    __syncthreads();
  }

  // ---- block epilogue: asum reduction + vlad atomics ----
#pragma unroll
  for (int mt = 0; mt < 4; ++mt) {
#pragma unroll
    for (int r = 0; r < 4; ++r) {
      float v = asum_reg[mt][r];
      v += __shfl_xor(v, 1, 64);
      v += __shfl_xor(v, 2, 64);
      v += __shfl_xor(v, 4, 64);
      v += __shfl_xor(v, 8, 64);
      if (l15 == 0) atomicAdd(&asum[n * Kk + 16*mt + 4*l4 + r], v);
    }
  }
#pragma unroll
  for (int mt = 0; mt < 4; ++mt)
#pragma unroll
    for (int tc = 0; tc < 2; ++tc)
#pragma unroll
      for (int r = 0; r < 4; ++r) {
        const int k = 16*mt + 4*l4 + r;
        const int c = 32*wv + 16*tc + l15;
        atomicAdd(&vlad[((size_t)n * Kk + k) * Cc + c], acc3[mt][tc][r]);
      }
}

__global__ void netvlad_epilogue(const float* __restrict__ vlad,
                                 const float* __restrict__ asum,
                                 const float* __restrict__ cent,
                                 float* __restrict__ out)
{
  const int n = blockIdx.x;
  const int t = threadIdx.x;
  const int k = t >> 2;       // 64 k, 4 threads each
  const int cq = t & 3;

  __shared__ float red[Kk][4];

  const float ak = asum[n * Kk + k];
  float4 v[8];
  float ss = 0.f;
#pragma unroll
  for (int i = 0; i < 8; ++i) {
    const int c = 4*cq + 16*i;
    float4 xv = *(const float4*)(vlad + ((size_t)n * Kk + k) * Cc + c);
    float4 cv = *(const float4*)(cent + k * Cc + c);
    float4 r;
    r.x = xv.x - ak * cv.x;
    r.y = xv.y - ak * cv.y;
    r.z = xv.z - ak * cv.z;
    r.w = xv.w - ak * cv.w;
    v[i] = r;
    ss += r.x*r.x + r.y*r.y + r.z*r.z + r.w*r.w;
  }
  red[k][cq] = ss;
  __syncthreads();
  const float s4 = red[k][0] + red[k][1] + red[k][2] + red[k][3];
  // intra-norm; global norm is exactly sqrt(K)=8 since rows are unit norm
  const float rn = rsqrtf(s4) * 0.125f;
#pragma unroll
  for (int i = 0; i < 8; ++i) {
    const int c = 4*cq + 16*i;
    float4 r = v[i];
    r.x *= rn; r.y *= rn; r.z *= rn; r.w *= rn;
    *(float4*)(out + (size_t)n * (Kk * Cc) + k * Cc + c) = r;
  }
}

extern "C" void kernel_launch(void* const* d_in, const int* in_sizes, int n_in,
                              void* d_out, int out_size, void* d_ws, size_t ws_size,
                              hipStream_t stream)
{
  const float* x    = (const float*)d_in[0];
  const float* w    = (const float*)d_in[1];
  const float* cent = (const float*)d_in[2];
  float* out  = (float*)d_out;
  float* vlad = (float*)d_ws;                          // N*K*C fp32
  float* asum = vlad + (size_t)Nn * Kk * Cc;           // N*K fp32

  const size_t zbytes = ((size_t)Nn * Kk * Cc + (size_t)Nn * Kk) * sizeof(float);
  hipMemsetAsync(d_ws, 0, zbytes, stream);

  netvlad_main<<<dim3(Ss / SB, Nn), 256, 0, stream>>>(x, w, vlad, asum);
  netvlad_epilogue<<<Nn, 256, 0, stream>>>(vlad, asum, cent, out);
}